// Round 6
// baseline (498.368 us; speedup 1.0000x reference)
//
#include <hip/hip_runtime.h>
#include <hip/hip_bf16.h>

typedef __hip_bfloat16 bf16;
typedef short bf16x8 __attribute__((ext_vector_type(8)));
typedef float f32x4 __attribute__((ext_vector_type(4)));

#define MFMA16(a,b,c) __builtin_amdgcn_mfma_f32_16x16x32_bf16(a,b,c,0,0,0)

__device__ __forceinline__ unsigned short f2us(float x){
    union{__hip_bfloat16 h; unsigned short u;} c; c.h = __float2bfloat16(x); return c.u;
}
__device__ __forceinline__ float us2f(unsigned short u){
    union{unsigned short u; __hip_bfloat16 h;} c; c.u = u; return __bfloat162float(c.h);
}
__device__ __forceinline__ uint4 pack8(float4 a, float4 b){
    union{unsigned short us[8]; uint4 v;} p;
    p.us[0]=f2us(a.x); p.us[1]=f2us(a.y); p.us[2]=f2us(a.z); p.us[3]=f2us(a.w);
    p.us[4]=f2us(b.x); p.us[5]=f2us(b.y); p.us[6]=f2us(b.z); p.us[7]=f2us(b.w);
    return p.v;
}

// ---------------------------------------------------------------------------
// prep: LDS-tiled transposes.
//  Wq/Wk: rows in s2-order  S = (d>>5)*256 + h*32 + (d&31)   (score-friendly)
//  Wv   : rows in p-order   p = d*8 + h                      (weighted-sum-friendly)
//  biases permuted to match; WoT pure transpose (if ws big enough).
// ---------------------------------------------------------------------------
__global__ __launch_bounds__(256) void prep_kernel(
    const float* __restrict__ Wq, const float* __restrict__ Wk,
    const float* __restrict__ Wv, const float* __restrict__ bq,
    const float* __restrict__ bk, const float* __restrict__ bv,
    const float* __restrict__ Wo,
    bf16* __restrict__ WqT, bf16* __restrict__ WkT, bf16* __restrict__ WvT,
    float* __restrict__ bqp, float* __restrict__ bkp, float* __restrict__ bvp,
    bf16* __restrict__ WoT)
{
    __shared__ float T[64][68];
    const int tid = threadIdx.x, bx = blockIdx.x;
    if (bx < 384) {
        const int mat = bx / 128, rem = bx % 128;
        const int c0 = (rem >> 5) * 64, n0 = (rem & 31) * 64;
        const float* W = (mat == 0) ? Wq : (mat == 1) ? Wk : Wv;
        bf16* WT = (mat == 0) ? WqT : (mat == 1) ? WkT : WvT;
        #pragma unroll
        for (int it = 0; it < 4; ++it) {
            int pp = tid + (it << 8);
            int cl = pp >> 4, n4 = (pp & 15) * 4;
            float4 f = *(const float4*)(W + (size_t)(c0 + cl) * 2048 + n0 + n4);
            T[cl][n4] = f.x; T[cl][n4+1] = f.y; T[cl][n4+2] = f.z; T[cl][n4+3] = f.w;
        }
        __syncthreads();
        const int h = n0 >> 8, d0 = n0 & 255;   // d0 is 64-aligned
        #pragma unroll
        for (int it = 0; it < 2; ++it) {
            int pp = tid + (it << 8);
            int j = pp >> 3, g = pp & 7;
            union{unsigned short us[8]; uint4 v;} pk;
            #pragma unroll
            for (int u = 0; u < 8; ++u) pk.us[u] = f2us(T[g*8+u][j]);
            int d = d0 + j;
            size_t row;
            if (mat < 2) row = (size_t)((d >> 5) * 256 + h * 32 + (d & 31)); // s2
            else         row = (size_t)(d * 8 + h);                          // p
            *(uint4*)(WT + row * 256 + c0 + g * 8) = pk.v;
        }
    } else if (bx < 387) {
        const int mat = bx - 384;
        const float* src = (mat == 0) ? bq : (mat == 1) ? bk : bv;
        float* dst = (mat == 0) ? bqp : (mat == 1) ? bkp : bvp;
        for (int n = tid; n < 2048; n += 256) {
            int h = n >> 8, d = n & 255;
            int idx = (mat < 2) ? ((d >> 5) * 256 + h * 32 + (d & 31)) : (d * 8 + h);
            dst[idx] = src[n];
        }
    } else {
        const int idx = bx - 387;
        const int k0 = (idx >> 2) * 64, c0 = (idx & 3) * 64;
        #pragma unroll
        for (int it = 0; it < 4; ++it) {
            int pp = tid + (it << 8);
            int kl = pp >> 4, c4 = (pp & 15) * 4;
            float4 f = *(const float4*)(Wo + (size_t)(k0 + kl) * 256 + c0 + c4);
            T[kl][c4] = f.x; T[kl][c4+1] = f.y; T[kl][c4+2] = f.z; T[kl][c4+3] = f.w;
        }
        __syncthreads();
        #pragma unroll
        for (int it = 0; it < 2; ++it) {
            int pp = tid + (it << 8);
            int j = pp >> 3, g = pp & 7;
            union{unsigned short us[8]; uint4 v;} pk;
            #pragma unroll
            for (int u = 0; u < 8; ++u) pk.us[u] = f2us(T[g*8+u][j]);
            *(uint4*)(WoT + (size_t)(c0 + j) * 2048 + k0 + g * 8) = pk.v;
        }
    }
}

// ---------------------------------------------------------------------------
// qk: 64 tokens/block, 512 threads, grid 256.
// Flipped GEMM: A-frag = W rows (global, s2-order), B-frag = X (LDS, reused
// across 2 M-tiles).  Epilogue writes QT/KT [tok][S-local] (pitch 528,
// 16B-unit swizzle (u+2*tok)&7).  Scores: 1 MFMA per token-pair per window,
// operands gathered as single b128 reads.  Softmax -> w bf16 [16384][64].
// ---------------------------------------------------------------------------
__global__ __launch_bounds__(512, 2) void qk_kernel(
    const float* __restrict__ Qin, const float* __restrict__ Kin,
    const int* __restrict__ mask,
    const bf16* __restrict__ WqTs, const bf16* __restrict__ WkTs,
    const float* __restrict__ bqs, const float* __restrict__ bks,
    bf16* __restrict__ wbf)
{
    __shared__ __align__(16) char smem[133120];
    char* const Xq = smem;             // [64][512B] swizzled (32 KB)
    char* const Xk = smem + 32768;     // 32 KB
    char* const QT = smem + 65536;     // [64 tok][528B] (33792)
    char* const KT = smem + 99328;     // 33792
    float* const RED = (float*)smem;   // [64][68] fp32, aliases Xq

    const int tid  = threadIdx.x;
    const int wave = tid >> 6, lane = tid & 63;
    const int quad = lane >> 4, l15 = lane & 15;
    const int tok0 = blockIdx.x * 64;

    #pragma unroll
    for (int it = 0; it < 4; ++it) {
        int pp = tid + (it << 9);
        int row = pp >> 5, g = pp & 31;
        const float* s = Qin + (size_t)(tok0 + row) * 256 + g * 8;
        *(uint4*)(Xq + row * 512 + ((g ^ (row & 7)) << 4)) =
            pack8(*(const float4*)s, *(const float4*)(s + 4));
        s = Kin + (size_t)(tok0 + row) * 256 + g * 8;
        *(uint4*)(Xk + row * 512 + ((g ^ (row & 7)) << 4)) =
            pack8(*(const float4*)s, *(const float4*)(s + 4));
    }
    __syncthreads();

    f32x4 sacc[4];
    #pragma unroll
    for (int p = 0; p < 4; ++p)
        #pragma unroll
        for (int i = 0; i < 4; ++i) sacc[p][i] = 0.f;

    for (int W = 0; W < 8; ++W) {
        #pragma unroll
        for (int mat = 0; mat < 2; ++mat) {
            const bf16* WT = mat ? WkTs : WqTs;
            const char* Xb = mat ? Xk : Xq;
            const float* bs = mat ? bks : bqs;
            char* RT = mat ? KT : QT;
            f32x4 acc[2][4];
            #pragma unroll
            for (int m = 0; m < 2; ++m)
                #pragma unroll
                for (int nt = 0; nt < 4; ++nt)
                    #pragma unroll
                    for (int i = 0; i < 4; ++i) acc[m][nt][i] = 0.f;
            #pragma unroll
            for (int Ks = 0; Ks < 8; ++Ks) {
                bf16x8 af[2];
                #pragma unroll
                for (int m = 0; m < 2; ++m)
                    af[m] = *(const bf16x8*)(WT +
                        (size_t)(W * 256 + (wave * 2 + m) * 16 + l15) * 256 + Ks * 32 + quad * 8);
                #pragma unroll
                for (int nt = 0; nt < 4; ++nt) {
                    int tok = nt * 16 + l15;
                    int G = (Ks * 4 + quad) ^ (tok & 7);
                    bf16x8 bfv = *(const bf16x8*)(Xb + tok * 512 + (G << 4));
                    #pragma unroll
                    for (int m = 0; m < 2; ++m)
                        acc[m][nt] = MFMA16(af[m], bfv, acc[m][nt]);
                }
            }
            #pragma unroll
            for (int m = 0; m < 2; ++m) {
                int Sb = (wave * 2 + m) * 16 + quad * 4;      // S_local of reg 0
                float4 b4 = *(const float4*)(bs + W * 256 + Sb);
                int u = (wave * 2 + m) * 2 + (quad >> 1);
                #pragma unroll
                for (int nt = 0; nt < 4; ++nt) {
                    int tok = nt * 16 + l15;
                    int up = (u & 24) | ((u + 2 * tok) & 7);
                    union{unsigned short us[4]; uint2 v;} pk;
                    pk.us[0] = f2us(acc[m][nt][0] + b4.x);
                    pk.us[1] = f2us(acc[m][nt][1] + b4.y);
                    pk.us[2] = f2us(acc[m][nt][2] + b4.z);
                    pk.us[3] = f2us(acc[m][nt][3] + b4.w);
                    *(uint2*)(RT + tok * 528 + up * 16 + (quad & 1) * 8) = pk.v;
                }
            }
        }
        __syncthreads();
        // scores: 4 token-pairs per wave, one 16x16x32 MFMA each (K = 32 d's)
        #pragma unroll
        for (int pp = 0; pp < 4; ++pp) {
            int tok = (wave * 4 + pp) * 2 + (l15 >> 3);
            int h = l15 & 7;
            int u = h * 4 + quad;
            int up = (u & 24) | ((u + 2 * tok) & 7);
            bf16x8 Aq = *(const bf16x8*)(QT + tok * 528 + up * 16);
            bf16x8 Bk = *(const bf16x8*)(KT + tok * 528 + up * 16);
            sacc[pp] = MFMA16(Aq, Bk, sacc[pp]);
        }
        __syncthreads();
    }

    // diagonal extraction -> RED[t][h*8+g]
    if ((quad >> 1) == (l15 >> 3)) {
        #pragma unroll
        for (int pp = 0; pp < 4; ++pp) {
            int tl = (wave * 4 + pp) * 2 + (l15 >> 3);
            #pragma unroll
            for (int i = 0; i < 4; ++i)
                RED[tl * 68 + ((quad & 1) * 4 + i) * 8 + (l15 & 7)] = sacc[pp][i];
        }
    }
    __syncthreads();
    // softmax: thread (tl, h); w stored bf16
    {
        const int tl = tid >> 3, hh = tid & 7;
        const int mk = mask[tok0 + tl];
        const float* r = RED + tl * 68 + hh * 8;
        float m = r[0];
        #pragma unroll
        for (int g = 1; g < 8; ++g) m = fmaxf(m, r[g]);
        float e[8], sum = 0.f;
        #pragma unroll
        for (int g = 0; g < 8; ++g) { e[g] = __expf((r[g] - m) * 0.0625f); sum += e[g]; }
        float inv = 1.f / sum;
        union{unsigned short us[8]; uint4 v;} pk;
        #pragma unroll
        for (int g = 0; g < 8; ++g) pk.us[g] = f2us(mk ? e[g] * inv : 0.125f);
        *(uint4*)(wbf + (size_t)(tok0 + tl) * 64 + hh * 8) = pk.v;
    }
}

// ---------------------------------------------------------------------------
// v_attn: 64 tokens/block, 512 threads, grid 256.  Flipped V-GEMM (A = WvT
// p-order from global, B = Xv LDS), VT [tok][p-local] round-trip, weighted
// sum reads all 8 g per b128, direct scrambled global stores.
// ---------------------------------------------------------------------------
__global__ __launch_bounds__(512, 4) void v_attn_kernel(
    const float* __restrict__ Vin,
    const bf16* __restrict__ WvT, const float* __restrict__ bvp,
    const bf16* __restrict__ wbf, bf16* __restrict__ A)
{
    __shared__ __align__(16) char smem[66560];
    char* const Xv = smem;             // 32 KB
    char* const VT = smem + 32768;     // [64 tok][528B] (33792)

    const int tid  = threadIdx.x;
    const int wave = tid >> 6, lane = tid & 63;
    const int quad = lane >> 4, l15 = lane & 15;
    const int tok0 = blockIdx.x * 64;
    const int t6 = tid & 63, dg = tid >> 6;

    #pragma unroll
    for (int it = 0; it < 4; ++it) {
        int pp = tid + (it << 9);
        int row = pp >> 5, g = pp & 31;
        const float* s = Vin + (size_t)(tok0 + row) * 256 + g * 8;
        *(uint4*)(Xv + row * 512 + ((g ^ (row & 7)) << 4)) =
            pack8(*(const float4*)s, *(const float4*)(s + 4));
    }
    unsigned wvp[32];   // packed bf16 pairs: w[h*8 + 2j], w[h*8 + 2j+1]
    {
        const uint4* wp = (const uint4*)(wbf + (size_t)(tok0 + t6) * 64);
        #pragma unroll
        for (int i = 0; i < 8; ++i) {
            uint4 v = wp[i];
            wvp[i*4] = v.x; wvp[i*4+1] = v.y; wvp[i*4+2] = v.z; wvp[i*4+3] = v.w;
        }
    }
    __syncthreads();

    const int gtok = tok0 + t6;
    const int bb = gtok >> 11, sr = gtok & 2047, sg = sr >> 3, jj = sr & 7;

    for (int W = 0; W < 8; ++W) {
        f32x4 acc[2][4];
        #pragma unroll
        for (int m = 0; m < 2; ++m)
            #pragma unroll
            for (int nt = 0; nt < 4; ++nt)
                #pragma unroll
                for (int i = 0; i < 4; ++i) acc[m][nt][i] = 0.f;
        #pragma unroll
        for (int Ks = 0; Ks < 8; ++Ks) {
            bf16x8 af[2];
            #pragma unroll
            for (int m = 0; m < 2; ++m)
                af[m] = *(const bf16x8*)(WvT +
                    (size_t)(W * 256 + (wave * 2 + m) * 16 + l15) * 256 + Ks * 32 + quad * 8);
            #pragma unroll
            for (int nt = 0; nt < 4; ++nt) {
                int tok = nt * 16 + l15;
                int G = (Ks * 4 + quad) ^ (tok & 7);
                bf16x8 bfv = *(const bf16x8*)(Xv + tok * 512 + (G << 4));
                #pragma unroll
                for (int m = 0; m < 2; ++m)
                    acc[m][nt] = MFMA16(af[m], bfv, acc[m][nt]);
            }
        }
        #pragma unroll
        for (int m = 0; m < 2; ++m) {
            int Sb = (wave * 2 + m) * 16 + quad * 4;
            float4 b4 = *(const float4*)(bvp + W * 256 + Sb);
            int u = (wave * 2 + m) * 2 + (quad >> 1);
            #pragma unroll
            for (int nt = 0; nt < 4; ++nt) {
                int tok = nt * 16 + l15;
                int up = (u & 24) | ((u + 2 * tok) & 7);
                union{unsigned short us[4]; uint2 v;} pk;
                pk.us[0] = f2us(acc[m][nt][0] + b4.x);
                pk.us[1] = f2us(acc[m][nt][1] + b4.y);
                pk.us[2] = f2us(acc[m][nt][2] + b4.z);
                pk.us[3] = f2us(acc[m][nt][3] + b4.w);
                *(uint2*)(VT + tok * 528 + up * 16 + (quad & 1) * 8) = pk.v;
            }
        }
        __syncthreads();
        // weighted sum: wave dg handles d = dg*4 + 0..3 of this window
        float vvf[4][8];
        #pragma unroll
        for (int dd = 0; dd < 4; ++dd) {
            int u = dg * 4 + dd;
            int up = (u & 24) | ((u + 2 * t6) & 7);
            bf16x8 v8 = *(const bf16x8*)(VT + t6 * 528 + up * 16);
            #pragma unroll
            for (int g = 0; g < 8; ++g) vvf[dd][g] = us2f((unsigned short)v8[g]);
        }
        #pragma unroll
        for (int h = 0; h < 8; ++h) {
            float wf[8];
            #pragma unroll
            for (int g2 = 0; g2 < 4; ++g2) {
                unsigned u2 = wvp[h * 4 + g2];
                wf[g2*2]   = us2f((unsigned short)(u2 & 0xffff));
                wf[g2*2+1] = us2f((unsigned short)(u2 >> 16));
            }
            union{unsigned short us[4]; uint2 v;} pk;
            #pragma unroll
            for (int dd = 0; dd < 4; ++dd) {
                float x = 0.f;
                #pragma unroll
                for (int g = 0; g < 8; ++g) x = fmaf(wf[g], vvf[dd][g], x);
                pk.us[dd] = f2us(x);
            }
            size_t r = ((size_t)bb << 11) + h * 256 + sg;
            *(uint2*)(A + r * 2048 + jj * 256 + W * 32 + dg * 4) = pk.v;
        }
        __syncthreads();
    }
}

// ---------------------------------------------------------------------------
// outproj: unchanged from R5.
// ---------------------------------------------------------------------------
__global__ __launch_bounds__(256) void outproj_kernel(
    const bf16* __restrict__ A, const bf16* __restrict__ WoT,
    const float* __restrict__ Wo, const float* __restrict__ bo,
    float* __restrict__ Out)
{
    __shared__ __align__(16) char smem[24576];
    char* const AsS = smem;
    char* const Ws  = smem + 8192;

    const int tid = threadIdx.x;
    const int wave = tid >> 6, lane = tid & 63, quad = lane >> 4, l15 = lane & 15;
    const int R = blockIdx.x >> 1, C = blockIdx.x & 1;
    const int row0 = R * 64, col0 = C * 128;

    f32x4 acc[4][2];
    #pragma unroll
    for (int mt = 0; mt < 4; ++mt)
        #pragma unroll
        for (int nt = 0; nt < 2; ++nt)
            #pragma unroll
            for (int i = 0; i < 4; ++i) acc[mt][nt][i] = 0.f;

    for (int kc = 0; kc < 32; ++kc) {
        __syncthreads();
        #pragma unroll
        for (int it = 0; it < 2; ++it) {
            int pp = tid + (it << 8);
            int rho = pp >> 3, g = pp & 7;
            *(uint4*)(AsS + rho * 128 + ((g ^ (rho & 7)) << 4)) =
                *(const uint4*)(A + (size_t)(row0 + rho) * 2048 + kc * 64 + g * 8);
        }
        if (WoT != nullptr) {
            #pragma unroll
            for (int it = 0; it < 4; ++it) {
                int pp = tid + (it << 8);
                int cl = pp >> 3, g = pp & 7;
                *(uint4*)(Ws + cl * 128 + ((g ^ (cl & 7)) << 4)) =
                    *(const uint4*)(WoT + (size_t)(col0 + cl) * 2048 + kc * 64 + g * 8);
            }
        } else {
            #pragma unroll
            for (int it = 0; it < 8; ++it) {
                int pp = tid + (it << 8);
                int kl = pp >> 5, c4 = (pp & 31) * 4;
                float4 f = *(const float4*)(Wo + (size_t)(kc * 64 + kl) * 256 + col0 + c4);
                float fv[4] = {f.x, f.y, f.z, f.w};
                #pragma unroll
                for (int u = 0; u < 4; ++u) {
                    int cl = c4 + u;
                    *(unsigned short*)(Ws + cl * 128 + (((kl >> 3) ^ (cl & 7)) << 4) + (kl & 7) * 2)
                        = f2us(fv[u]);
                }
            }
        }
        __syncthreads();
        #pragma unroll
        for (int ks = 0; ks < 2; ++ks) {
            bf16x8 a[4], b[2];
            #pragma unroll
            for (int mt = 0; mt < 4; ++mt) {
                int row = mt * 16 + l15;
                int G = (ks * 4 + quad) ^ (row & 7);
                a[mt] = *(const bf16x8*)(AsS + row * 128 + (G << 4));
            }
            #pragma unroll
            for (int nt = 0; nt < 2; ++nt) {
                int cl = wave * 32 + nt * 16 + l15;
                int G = (ks * 4 + quad) ^ (cl & 7);
                b[nt] = *(const bf16x8*)(Ws + cl * 128 + (G << 4));
            }
            #pragma unroll
            for (int mt = 0; mt < 4; ++mt)
                #pragma unroll
                for (int nt = 0; nt < 2; ++nt)
                    acc[mt][nt] = MFMA16(a[mt], b[nt], acc[mt][nt]);
        }
    }
    #pragma unroll
    for (int nt = 0; nt < 2; ++nt) {
        int col = col0 + wave * 32 + nt * 16 + l15;
        float bias = bo[col];
        #pragma unroll
        for (int mt = 0; mt < 4; ++mt) {
            int r0 = row0 + mt * 16 + quad * 4;
            #pragma unroll
            for (int i = 0; i < 4; ++i)
                Out[(size_t)(r0 + i) * 256 + col] = acc[mt][nt][i] + bias;
        }
    }
}

// ---------------------------------------------------------------------------
extern "C" void kernel_launch(void* const* d_in, const int* in_sizes, int n_in,
                              void* d_out, int out_size, void* d_ws, size_t ws_size,
                              hipStream_t stream) {
    const float* query = (const float*)d_in[0];
    const float* key   = (const float*)d_in[1];
    const float* value = (const float*)d_in[2];
    const int*   mask  = (const int*)  d_in[3];
    const float* Wq = (const float*)d_in[4];  const float* bq = (const float*)d_in[5];
    const float* Wk = (const float*)d_in[6];  const float* bk = (const float*)d_in[7];
    const float* Wv = (const float*)d_in[8];  const float* bv = (const float*)d_in[9];
    const float* Wo = (const float*)d_in[10]; const float* bo = (const float*)d_in[11];

    // d_out doubles as scratch; consumed before outproj overwrites d_out.
    char* dc = (char*)d_out;
    bf16*  WqTs = (bf16*)dc;                   // [2048][256] bf16, 1 MB (s2-order)
    bf16*  WkTs = (bf16*)(dc + 1048576);
    bf16*  WvT  = (bf16*)(dc + 2097152);       // p-order
    float* bqs  = (float*)(dc + 3145728);
    float* bks  = (float*)(dc + 3153920);
    float* bvp  = (float*)(dc + 3162112);
    bf16*  wbf  = (bf16*)(dc + 3170304);       // [16384][64] bf16, 2 MB

    bf16* A = (bf16*)d_ws;                     // scrambled x_att, 64 MB
    const bool big = ws_size >= (67108864ull + 1048576ull);
    bf16* WoT = big ? (bf16*)((char*)d_ws + 67108864) : nullptr;

    prep_kernel<<<big ? 515 : 387, 256, 0, stream>>>(
        Wq, Wk, Wv, bq, bk, bv, Wo, WqTs, WkTs, WvT, bqs, bks, bvp, WoT);
    qk_kernel<<<256, 512, 0, stream>>>(
        query, key, mask, WqTs, WkTs, bqs, bks, wbf);
    v_attn_kernel<<<256, 512, 0, stream>>>(value, WvT, bvp, wbf, A);
    outproj_kernel<<<512, 256, 0, stream>>>(A, WoT, Wo, bo, (float*)d_out);
}